// Round 17
// baseline (146.310 us; speedup 1.0000x reference)
//
#include <hip/hip_runtime.h>
#include <hip/hip_bf16.h>

#define DIMSZ 256
#define HID 4096
#define BATCH 4
#define SEQ 2048
#define NCH 64      // chunks per sequence (carry granularity)
#define CLEN 32     // chunk length
#define SPLITK2 4   // K-splits for fused GEMM2
#define KCHUNK (HID / SPLITK2)   // 1024 channels per block
#define BM2 64      // timesteps per fused-GEMM2 block (= 2 chunks)

typedef __bf16 bf16_t;
typedef __bf16 bf16x4 __attribute__((ext_vector_type(4)));
typedef __bf16 bf16x8 __attribute__((ext_vector_type(8)));
typedef float  f32x4  __attribute__((ext_vector_type(4)));

__device__ __forceinline__ float sigmoidf_dev(float x) {
    return 1.0f / (1.0f + __expf(-x));
}

// async global->LDS, 16B/lane. Global src is per-lane; LDS dest = wave-uniform
// base + lane*16 (hardware-defined).
__device__ __forceinline__ void load_lds16(const bf16_t* g, bf16_t* l) {
    __builtin_amdgcn_global_load_lds(
        (const __attribute__((address_space(1))) void*)g,
        (__attribute__((address_space(3))) void*)l,
        16, 0, 0);
}

__device__ __forceinline__ bf16x8 cvt8(const float* p) {
    bf16x8 o;
    #pragma unroll
    for (int j = 0; j < 8; j++) o[j] = (bf16_t)p[j];
    return o;
}

// ---------------- prep: fused fp32->bf16 convert + MFMA-frag swizzle ----------------
__global__ void prep_kernel(const float* __restrict__ x,
                            const float* __restrict__ WB,
                            const float* __restrict__ WC,
                            bf16_t* __restrict__ xt,
                            bf16_t* __restrict__ WBt,
                            bf16_t* __restrict__ Wt) {
    int i = blockIdx.x * blockDim.x + threadIdx.x;   // 524288
    if (i < 262144) {                                // xt
        int lane = i & 63, m16 = (i >> 6) & 511, ks = i >> 15;
        int row = m16 * 16 + (lane & 15);
        int k   = ks * 32 + (lane >> 4) * 8;
        *(bf16x8*)&xt[(size_t)i * 8] = cvt8(&x[(size_t)row * DIMSZ + k]);
    } else if (i < 393216) {                         // WBt
        int j = i - 262144;
        int lane = j & 63, n16 = (j >> 6) & 255, ks = j >> 14;
        int row = n16 * 16 + (lane & 15);
        int k   = ks * 32 + (lane >> 4) * 8;
        *(bf16x8*)&WBt[(size_t)j * 8] = cvt8(&WB[(size_t)row * DIMSZ + k]);
    } else {                                         // Wt
        int j = i - 393216;
        int lane = j & 63, g = (j >> 6) & 15, ks = j >> 10;
        int row = g * 16 + (lane & 15);
        int k   = ks * 32 + (lane >> 4) * 8;
        *(bf16x8*)&Wt[(size_t)j * 8] = cvt8(&WC[(size_t)row * HID + k]);
    }
}

// ---------------- GEMM1 fused: b = x@WB^T + bB (bf16, chunk-blocked out), + totals ----
// m97-style K-loop: double-buffered global_load_lds staging (R12, proven −2.2 µs)
// + T5 setprio around the frag-read+MFMA region (R15's gemm2 mechanism: 8
// phase-staggered blocks/CU -> MFMA-cluster waves win issue vs staging waves).
__global__ __launch_bounds__(256)
void gemm1_fused(const bf16_t* __restrict__ xt, const bf16_t* __restrict__ WBt,
                 const float* __restrict__ bias, const float* __restrict__ Adecay,
                 bf16_t* __restrict__ Cg, float* __restrict__ totals)
{
    constexpr int LDT = 136;                // elems; 272 B row stride (16B-aligned)
    __shared__ bf16_t tile[128 * LDT];      // 34.8 KB; elems [0,16384) = K-loop staging

    const int tid = threadIdx.x, wave = tid >> 6, lane = tid & 63;
    const int wm = wave >> 1, wn = wave & 1, q = lane >> 4, r16 = lane & 15;
    const int mBase = blockIdx.x * 128, nBase = blockIdx.y * 128;
    const int batch = mBase >> 11, tIn = mBase & 2047;
    const int cg0 = tIn >> 5;               // first of 4 chunks this block covers

    auto stage = [&](int ks, int buf) {
        #pragma unroll
        for (int i = 0; i < 2; i++) {
            const int g = wave * 2 + i;
            load_lds16(&xt[(((size_t)ks * 512 + blockIdx.x * 8 + g) * 64 + lane) * 8],
                       &tile[buf * 8192 + g * 512]);
            load_lds16(&WBt[(((size_t)ks * 256 + blockIdx.y * 8 + g) * 64 + lane) * 8],
                       &tile[buf * 8192 + 4096 + g * 512]);
        }
    };

    stage(0, 0);

    f32x4 acc[4][4] = {};
    int cur = 0;
    #pragma unroll
    for (int ks = 0; ks < 8; ks++) {
        __syncthreads();                     // buf[cur] DMA landed; prev reads drained
        if (ks < 7) stage(ks + 1, cur ^ 1);  // next tile in flight under this step
        __builtin_amdgcn_s_setprio(1);
        bf16x8 af[4], bfr[4];
        #pragma unroll
        for (int mt = 0; mt < 4; mt++)
            af[mt] = *(const bf16x8*)&tile[cur * 8192 + (wm * 4 + mt) * 512 + lane * 8];
        #pragma unroll
        for (int nt = 0; nt < 4; nt++)
            bfr[nt] = *(const bf16x8*)&tile[cur * 8192 + 4096 + (wn * 4 + nt) * 512 + lane * 8];
        #pragma unroll
        for (int mt = 0; mt < 4; mt++)
            #pragma unroll
            for (int nt = 0; nt < 4; nt++)
                acc[mt][nt] = __builtin_amdgcn_mfma_f32_16x16x32_bf16(
                    af[mt], bfr[nt], acc[mt][nt], 0, 0, 0);
        __builtin_amdgcn_s_setprio(0);
        cur ^= 1;
    }
    __syncthreads();   // all staging reads drained before tile is reused below

    // acc (+bias) -> [ch][t] tile, packed b64 (4 consecutive t per acc quad)
    #pragma unroll
    for (int nt = 0; nt < 4; nt++) {
        const int chl = wn * 64 + nt * 16 + r16;
        const float bv = bias[nBase + chl];
        #pragma unroll
        for (int mt = 0; mt < 4; mt++) {
            const int t0 = wm * 64 + mt * 16 + q * 4;
            bf16x4 pk;
            #pragma unroll
            for (int rg = 0; rg < 4; rg++)
                pk[rg] = (bf16_t)(acc[mt][nt][rg] + bv);
            *(bf16x4*)&tile[chl * LDT + t0] = pk;
        }
    }
    __syncthreads();

    // writeback: chunk-blocked bbuf, consecutive lanes -> consecutive 16 B
    #pragma unroll
    for (int p = 0; p < 8; p++) {
        const int cc = p >> 1;
        const int tt = (p & 1) * 256 + tid;
        const int ch = tt >> 2, oo = tt & 3;
        *(bf16x8*)&Cg[((size_t)(batch * NCH + cg0 + cc) * HID + nBase + ch) * 32 + oo * 8] =
            *(const bf16x8*)&tile[ch * LDT + cc * 32 + oo * 8];
    }

    // chunk totals: vectorized b128 reads along t
    #pragma unroll
    for (int t = 0; t < 2; t++) {
        const int task = tid + t * 256;
        const int ch = task & 127, ck = task >> 7;
        const float a = sigmoidf_dev(Adecay[nBase + ch]);
        float tot = 0.f;
        #pragma unroll
        for (int o = 0; o < 4; o++) {
            bf16x8 v8 = *(const bf16x8*)&tile[ch * LDT + ck * CLEN + o * 8];
            #pragma unroll
            for (int j = 0; j < 8; j++)
                tot = a * tot + (float)v8[j];
        }
        totals[(size_t)(batch * NCH + cg0 + ck) * HID + nBase + ch] = tot;
    }
}

// ---------------- scan over chunk carries, register-batched ----------------
__global__ void scan_carries_kernel(const float* __restrict__ totals,
                                    const float* __restrict__ Adecay,
                                    float* __restrict__ carries)
{
    int gid = blockIdx.x * 64 + threadIdx.x;   // BATCH*HID
    int ch    = gid & (HID - 1);
    int batch = gid >> 12;
    float a = sigmoidf_dev(Adecay[ch]);
    float aC = a;
    #pragma unroll
    for (int i = 0; i < 5; i++) aC *= aC;      // a^32

    float v[NCH];
    #pragma unroll
    for (int c = 0; c < NCH; c++)
        v[c] = totals[(size_t)(batch * NCH + c) * HID + ch];

    float carry = 0.f;
    #pragma unroll
    for (int c = 0; c < NCH; c++) {
        carries[(size_t)(batch * NCH + c) * HID + ch] = carry;
        carry = aC * carry + v[c];
    }
}

// ---------------- fused scan + GEMM2 split-K (2-chunk blocks, Wt-shared MFMA) --------
// R15 champion (132.5): Wt-shared MFMA + pipelined scan(s+1)||mfma(s) + T5
// setprio around MFMA clusters. __syncthreads barriers (R16's raw-barrier
// variant regressed: sched_barrier(0) pinning defeats compiler scheduling).
__global__ __launch_bounds__(256, 2)
void gemm2_fused(const bf16_t* __restrict__ bv, const bf16_t* __restrict__ Wt,
                 const float* __restrict__ Adecay, const float* __restrict__ carries,
                 bf16_t* __restrict__ P)
{
    constexpr int CKSTRIDE = CLEN * 32 + 32;   // 1056: +64B stagger between ck slabs
    constexpr int CHOFF = 8 * CKSTRIDE;        // per-chunk half (8448 elems)
    __shared__ bf16_t hs[2][2 * CHOFF];        // 2 ping x 2 chunks = 67.6 KB

    const int tid = threadIdx.x, wave = tid >> 6, lane = tid & 63;
    const int q = lane >> 4, r16 = lane & 15;
    const int mBase = blockIdx.x * BM2;
    const int kBase = blockIdx.y * KCHUNK;
    const int batch = mBase >> 11, tIn = mBase & 2047;
    const int chunk0 = tIn >> 5;               // block covers chunk0, chunk0+1

    const size_t base0 = ((size_t)(batch * NCH + chunk0) * HID + kBase + tid) * 32;
    const size_t base1 = base0 + (size_t)HID * 32;

    bf16x8 rA[8], rB[8];   // [0..3]=chunk0, [4..7]=chunk1

    #define LOAD_SLAB(R, S)                                                   \
        do {                                                                  \
            _Pragma("unroll")                                                 \
            for (int o = 0; o < 4; o++) {                                     \
                R[o]     = *(const bf16x8*)&bv[base0 + (S) * 8192 + o * 8];   \
                R[4 + o] = *(const bf16x8*)&bv[base1 + (S) * 8192 + o * 8];   \
            }                                                                 \
        } while (0)

    LOAD_SLAB(rA, 0);      // longest-latency first

    float aD[4], sd0[4], sd1[4];
    #pragma unroll
    for (int s = 0; s < 4; s++) {
        const int c = kBase + s * 256 + tid;
        aD[s]  = Adecay[c];
        sd0[s] = carries[(size_t)(batch * NCH + chunk0) * HID + c];
        sd1[s] = carries[(size_t)(batch * NCH + chunk0 + 1) * HID + c];
    }

    LOAD_SLAB(rB, 1);

    f32x4 acc[2][2][4] = {};

    #define SCAN_SLAB(R, S, PG)                                               \
        do {                                                                  \
            const float a = sigmoidf_dev(aD[S]);                              \
            float st0 = sd0[S], st1 = sd1[S];                                 \
            bf16_t* hw0 = &hs[PG][(tid >> 5) * CKSTRIDE];                     \
            bf16_t* hw1 = hw0 + CHOFF;                                        \
            const int cho = (tid >> 3) & 3, chi = tid & 7;                    \
            _Pragma("unroll")                                                 \
            for (int o = 0; o < 4; o++) {                                     \
                _Pragma("unroll")                                             \
                for (int j = 0; j < 8; j++) {                                 \
                    const int t = o * 8 + j;                                  \
                    const int sw = t * 32 + ((cho ^ ((t >> 2) & 3)) << 3) + chi; \
                    st0 = a * st0 + (float)R[o][j];                           \
                    hw0[sw] = (bf16_t)st0;                                    \
                    st1 = a * st1 + (float)R[4 + o][j];                       \
                    hw1[sw] = (bf16_t)st1;                                    \
                }                                                             \
            }                                                                 \
        } while (0)

    auto mfma_phase = [&](const bf16_t* hb, int s) {
        const int ksBase = (kBase >> 5) + s * 8;
        __builtin_amdgcn_s_setprio(1);
        #pragma unroll 2
        for (int cki = 0; cki < 8; cki++) {
            bf16x8 af[2][2], bfr[4];
            #pragma unroll
            for (int nt = 0; nt < 4; nt++)
                bfr[nt] = *(const bf16x8*)&Wt[
                    (((size_t)(ksBase + cki) * 16 + wave * 4 + nt) * 64 + lane) * 8];
            #pragma unroll
            for (int c = 0; c < 2; c++)
                #pragma unroll
                for (int mt = 0; mt < 2; mt++)
                    af[c][mt] = *(const bf16x8*)&hb[c * CHOFF + cki * CKSTRIDE
                                 + (mt * 16 + r16) * 32 + ((q ^ (r16 >> 2)) << 3)];
            #pragma unroll
            for (int c = 0; c < 2; c++)
                #pragma unroll
                for (int mt = 0; mt < 2; mt++)
                    #pragma unroll
                    for (int nt = 0; nt < 4; nt++)
                        acc[c][mt][nt] = __builtin_amdgcn_mfma_f32_16x16x32_bf16(
                            af[c][mt], bfr[nt], acc[c][mt][nt], 0, 0, 0);
        }
        __builtin_amdgcn_s_setprio(0);
    };

    // prologue: scan(0) exposed (nothing to overlap yet)
    SCAN_SLAB(rA, 0, 0);
    __syncthreads();

    // P1: load(2) || scan(1)->hs[1] || mfma(0, hs[0])
    LOAD_SLAB(rA, 2);
    SCAN_SLAB(rB, 1, 1);
    mfma_phase(&hs[0][0], 0);
    __syncthreads();

    // P2: load(3) || scan(2)->hs[0] || mfma(1, hs[1])
    LOAD_SLAB(rB, 3);
    SCAN_SLAB(rA, 2, 0);
    mfma_phase(&hs[1][0], 1);
    __syncthreads();

    // P3: scan(3)->hs[1] || mfma(2, hs[0])
    SCAN_SLAB(rB, 3, 1);
    mfma_phase(&hs[0][0], 2);
    __syncthreads();

    // P4: mfma(3, hs[1]); epilogue writes hs[0] (its readers drained at P3 barrier)
    mfma_phase(&hs[1][0], 3);
    #pragma unroll
    for (int nt = 0; nt < 4; nt++) {
        const int col = wave * 64 + nt * 16 + r16;
        #pragma unroll
        for (int c = 0; c < 2; c++)
            #pragma unroll
            for (int mt = 0; mt < 2; mt++)
                #pragma unroll
                for (int rg = 0; rg < 4; rg++)
                    hs[0][(c * 32 + mt * 16 + q * 4 + rg) * 264 + col] =
                        (bf16_t)acc[c][mt][nt][rg];
    }
    __syncthreads();

    bf16_t* Pb = P + (size_t)blockIdx.y * (BATCH * SEQ) * DIMSZ;
    #pragma unroll
    for (int p = 0; p < 8; p++) {
        const int task = p * 256 + tid;
        const int r = task >> 5, g8 = (task & 31) << 3;
        *(bf16x8*)&Pb[(size_t)(mBase + r) * DIMSZ + g8] =
            *(const bf16x8*)&hs[0][r * 264 + g8];
    }
    #undef LOAD_SLAB
    #undef SCAN_SLAB
}

// ---------------- reduce bf16 partials + bias -> fp32 d_out ----------------
__global__ void reduce_out_kernel(const bf16_t* __restrict__ P,
                                  const float* __restrict__ bias,
                                  float* __restrict__ out, int nTask) {
    int i = blockIdx.x * blockDim.x + threadIdx.x;   // M*256/8
    if (i >= nTask) return;
    int n8 = (i & 31) << 3;
    size_t off = (size_t)i * 8;
    float v[8];
    #pragma unroll
    for (int j = 0; j < 8; j++) v[j] = bias[n8 + j];
    #pragma unroll
    for (int sp = 0; sp < SPLITK2; sp++) {
        bf16x8 p = *(const bf16x8*)&P[(size_t)sp * (BATCH * SEQ) * DIMSZ + off];
        #pragma unroll
        for (int j = 0; j < 8; j++) v[j] += (float)p[j];
    }
    float4* o4 = (float4*)&out[off];
    o4[0] = make_float4(v[0], v[1], v[2], v[3]);
    o4[1] = make_float4(v[4], v[5], v[6], v[7]);
}

extern "C" void kernel_launch(void* const* d_in, const int* in_sizes, int n_in,
                              void* d_out, int out_size, void* d_ws, size_t ws_size,
                              hipStream_t stream)
{
    const float* x  = (const float*)d_in[0];
    const float* WB = (const float*)d_in[1];
    const float* bB = (const float*)d_in[2];
    const float* WC = (const float*)d_in[3];
    const float* bC = (const float*)d_in[4];
    const float* A  = (const float*)d_in[5];

    char* ws = (char*)d_ws;
    size_t off = 0;
    bf16_t* xt   = (bf16_t*)(ws + off); off += (size_t)BATCH * SEQ * DIMSZ * 2;  // 4 MB
    bf16_t* WBt  = (bf16_t*)(ws + off); off += (size_t)HID * DIMSZ * 2;          // 2 MB
    bf16_t* Wt   = (bf16_t*)(ws + off); off += (size_t)DIMSZ * HID * 2;          // 2 MB
    bf16_t* bbuf = (bf16_t*)(ws + off); off += (size_t)BATCH * SEQ * HID * 2;    // 64 MB, chunk-blocked
    bf16_t* partials = (bf16_t*)(ws + off); off += (size_t)SPLITK2 * BATCH * SEQ * DIMSZ * 2; // 16.75 MB
    float* totals   = (float*)(ws + off); off += (size_t)BATCH * NCH * HID * 4;
    float* carries  = (float*)(ws + off); off += (size_t)BATCH * NCH * HID * 4;

    const int M = BATCH * SEQ;   // 8192

    prep_kernel<<<2048, 256, 0, stream>>>(x, WB, WC, xt, WBt, Wt);

    dim3 g1(M / 128, HID / 128);
    gemm1_fused<<<g1, 256, 0, stream>>>(xt, WBt, bB, A, bbuf, totals);

    scan_carries_kernel<<<256, 64, 0, stream>>>(totals, A, carries);

    dim3 g2(M / BM2, SPLITK2);
    gemm2_fused<<<g2, 256, 0, stream>>>(bbuf, Wt, A, carries, partials);

    int nTask = M * DIMSZ / 8;
    reduce_out_kernel<<<(nTask + 255) / 256, 256, 0, stream>>>(
        partials, bC, (float*)d_out, nTask);
}

// Round 18
// 132.269 us; speedup vs baseline: 1.1062x; 1.1062x over previous
//
#include <hip/hip_runtime.h>
#include <hip/hip_bf16.h>

#define DIMSZ 256
#define HID 4096
#define BATCH 4
#define SEQ 2048
#define NCH 64      // chunks per sequence (carry granularity)
#define CLEN 32     // chunk length
#define SPLITK2 4   // K-splits for fused GEMM2
#define KCHUNK (HID / SPLITK2)   // 1024 channels per block
#define BM2 64      // timesteps per fused-GEMM2 block (= 2 chunks)

typedef __bf16 bf16_t;
typedef __bf16 bf16x4 __attribute__((ext_vector_type(4)));
typedef __bf16 bf16x8 __attribute__((ext_vector_type(8)));
typedef float  f32x4  __attribute__((ext_vector_type(4)));

__device__ __forceinline__ float sigmoidf_dev(float x) {
    return 1.0f / (1.0f + __expf(-x));
}

// async global->LDS, 16B/lane. Global src is per-lane; LDS dest = wave-uniform
// base + lane*16 (hardware-defined).
__device__ __forceinline__ void load_lds16(const bf16_t* g, bf16_t* l) {
    __builtin_amdgcn_global_load_lds(
        (const __attribute__((address_space(1))) void*)g,
        (__attribute__((address_space(3))) void*)l,
        16, 0, 0);
}

__device__ __forceinline__ bf16x8 cvt8(const float* p) {
    bf16x8 o;
    #pragma unroll
    for (int j = 0; j < 8; j++) o[j] = (bf16_t)p[j];
    return o;
}

// ---------------- prep: fused fp32->bf16 convert + MFMA-frag swizzle ----------------
__global__ void prep_kernel(const float* __restrict__ x,
                            const float* __restrict__ WB,
                            const float* __restrict__ WC,
                            bf16_t* __restrict__ xt,
                            bf16_t* __restrict__ WBt,
                            bf16_t* __restrict__ Wt) {
    int i = blockIdx.x * blockDim.x + threadIdx.x;   // 524288
    if (i < 262144) {                                // xt
        int lane = i & 63, m16 = (i >> 6) & 511, ks = i >> 15;
        int row = m16 * 16 + (lane & 15);
        int k   = ks * 32 + (lane >> 4) * 8;
        *(bf16x8*)&xt[(size_t)i * 8] = cvt8(&x[(size_t)row * DIMSZ + k]);
    } else if (i < 393216) {                         // WBt
        int j = i - 262144;
        int lane = j & 63, n16 = (j >> 6) & 255, ks = j >> 14;
        int row = n16 * 16 + (lane & 15);
        int k   = ks * 32 + (lane >> 4) * 8;
        *(bf16x8*)&WBt[(size_t)j * 8] = cvt8(&WB[(size_t)row * DIMSZ + k]);
    } else {                                         // Wt
        int j = i - 393216;
        int lane = j & 63, g = (j >> 6) & 15, ks = j >> 10;
        int row = g * 16 + (lane & 15);
        int k   = ks * 32 + (lane >> 4) * 8;
        *(bf16x8*)&Wt[(size_t)j * 8] = cvt8(&WC[(size_t)row * HID + k]);
    }
}

// ---------------- GEMM1 fused: b = x@WB^T + bB (bf16, chunk-blocked out), + totals ----
// m97-style K-loop: double-buffered global_load_lds staging (R12, proven −2.2 µs).
// NO setprio here (R17: −14 µs — 8 lockstep blocks/CU starve each other's staging).
__global__ __launch_bounds__(256)
void gemm1_fused(const bf16_t* __restrict__ xt, const bf16_t* __restrict__ WBt,
                 const float* __restrict__ bias, const float* __restrict__ Adecay,
                 bf16_t* __restrict__ Cg, float* __restrict__ totals)
{
    constexpr int LDT = 136;                // elems; 272 B row stride (16B-aligned)
    __shared__ bf16_t tile[128 * LDT];      // 34.8 KB; elems [0,16384) = K-loop staging

    const int tid = threadIdx.x, wave = tid >> 6, lane = tid & 63;
    const int wm = wave >> 1, wn = wave & 1, q = lane >> 4, r16 = lane & 15;
    const int mBase = blockIdx.x * 128, nBase = blockIdx.y * 128;
    const int batch = mBase >> 11, tIn = mBase & 2047;
    const int cg0 = tIn >> 5;               // first of 4 chunks this block covers

    auto stage = [&](int ks, int buf) {
        #pragma unroll
        for (int i = 0; i < 2; i++) {
            const int g = wave * 2 + i;
            load_lds16(&xt[(((size_t)ks * 512 + blockIdx.x * 8 + g) * 64 + lane) * 8],
                       &tile[buf * 8192 + g * 512]);
            load_lds16(&WBt[(((size_t)ks * 256 + blockIdx.y * 8 + g) * 64 + lane) * 8],
                       &tile[buf * 8192 + 4096 + g * 512]);
        }
    };

    stage(0, 0);

    f32x4 acc[4][4] = {};
    int cur = 0;
    #pragma unroll
    for (int ks = 0; ks < 8; ks++) {
        __syncthreads();                     // buf[cur] DMA landed; prev reads drained
        if (ks < 7) stage(ks + 1, cur ^ 1);  // next tile in flight under this step
        bf16x8 af[4], bfr[4];
        #pragma unroll
        for (int mt = 0; mt < 4; mt++)
            af[mt] = *(const bf16x8*)&tile[cur * 8192 + (wm * 4 + mt) * 512 + lane * 8];
        #pragma unroll
        for (int nt = 0; nt < 4; nt++)
            bfr[nt] = *(const bf16x8*)&tile[cur * 8192 + 4096 + (wn * 4 + nt) * 512 + lane * 8];
        #pragma unroll
        for (int mt = 0; mt < 4; mt++)
            #pragma unroll
            for (int nt = 0; nt < 4; nt++)
                acc[mt][nt] = __builtin_amdgcn_mfma_f32_16x16x32_bf16(
                    af[mt], bfr[nt], acc[mt][nt], 0, 0, 0);
        cur ^= 1;
    }
    __syncthreads();   // all staging reads drained before tile is reused below

    // acc (+bias) -> [ch][t] tile, packed b64 (4 consecutive t per acc quad)
    #pragma unroll
    for (int nt = 0; nt < 4; nt++) {
        const int chl = wn * 64 + nt * 16 + r16;
        const float bv = bias[nBase + chl];
        #pragma unroll
        for (int mt = 0; mt < 4; mt++) {
            const int t0 = wm * 64 + mt * 16 + q * 4;
            bf16x4 pk;
            #pragma unroll
            for (int rg = 0; rg < 4; rg++)
                pk[rg] = (bf16_t)(acc[mt][nt][rg] + bv);
            *(bf16x4*)&tile[chl * LDT + t0] = pk;
        }
    }
    __syncthreads();

    // writeback: chunk-blocked bbuf, consecutive lanes -> consecutive 16 B
    #pragma unroll
    for (int p = 0; p < 8; p++) {
        const int cc = p >> 1;
        const int tt = (p & 1) * 256 + tid;
        const int ch = tt >> 2, oo = tt & 3;
        *(bf16x8*)&Cg[((size_t)(batch * NCH + cg0 + cc) * HID + nBase + ch) * 32 + oo * 8] =
            *(const bf16x8*)&tile[ch * LDT + cc * 32 + oo * 8];
    }

    // chunk totals: vectorized b128 reads along t
    #pragma unroll
    for (int t = 0; t < 2; t++) {
        const int task = tid + t * 256;
        const int ch = task & 127, ck = task >> 7;
        const float a = sigmoidf_dev(Adecay[nBase + ch]);
        float tot = 0.f;
        #pragma unroll
        for (int o = 0; o < 4; o++) {
            bf16x8 v8 = *(const bf16x8*)&tile[ch * LDT + ck * CLEN + o * 8];
            #pragma unroll
            for (int j = 0; j < 8; j++)
                tot = a * tot + (float)v8[j];
        }
        totals[(size_t)(batch * NCH + cg0 + ck) * HID + nBase + ch] = tot;
    }
}

// ---------------- scan over chunk carries, register-batched ----------------
__global__ void scan_carries_kernel(const float* __restrict__ totals,
                                    const float* __restrict__ Adecay,
                                    float* __restrict__ carries)
{
    int gid = blockIdx.x * 64 + threadIdx.x;   // BATCH*HID
    int ch    = gid & (HID - 1);
    int batch = gid >> 12;
    float a = sigmoidf_dev(Adecay[ch]);
    float aC = a;
    #pragma unroll
    for (int i = 0; i < 5; i++) aC *= aC;      // a^32

    float v[NCH];
    #pragma unroll
    for (int c = 0; c < NCH; c++)
        v[c] = totals[(size_t)(batch * NCH + c) * HID + ch];

    float carry = 0.f;
    #pragma unroll
    for (int c = 0; c < NCH; c++) {
        carries[(size_t)(batch * NCH + c) * HID + ch] = carry;
        carry = aC * carry + v[c];
    }
}

// ---------------- fused scan + GEMM2 split-K (2-chunk blocks, Wt-shared MFMA) --------
// R15 champion (132.5): Wt-shared MFMA (halved L2 traffic) + pipelined
// scan(s+1)||mfma(s) via hs ping-pong + T5 setprio around MFMA clusters
// (2 phase-staggered blocks/CU -> MFMA waves win issue arbitration, −4.9 µs).
// __syncthreads barriers (R16's raw-barrier variant regressed: sched_barrier(0)
// pinning defeats compiler scheduling).
__global__ __launch_bounds__(256, 2)
void gemm2_fused(const bf16_t* __restrict__ bv, const bf16_t* __restrict__ Wt,
                 const float* __restrict__ Adecay, const float* __restrict__ carries,
                 bf16_t* __restrict__ P)
{
    constexpr int CKSTRIDE = CLEN * 32 + 32;   // 1056: +64B stagger between ck slabs
    constexpr int CHOFF = 8 * CKSTRIDE;        // per-chunk half (8448 elems)
    __shared__ bf16_t hs[2][2 * CHOFF];        // 2 ping x 2 chunks = 67.6 KB

    const int tid = threadIdx.x, wave = tid >> 6, lane = tid & 63;
    const int q = lane >> 4, r16 = lane & 15;
    const int mBase = blockIdx.x * BM2;
    const int kBase = blockIdx.y * KCHUNK;
    const int batch = mBase >> 11, tIn = mBase & 2047;
    const int chunk0 = tIn >> 5;               // block covers chunk0, chunk0+1

    const size_t base0 = ((size_t)(batch * NCH + chunk0) * HID + kBase + tid) * 32;
    const size_t base1 = base0 + (size_t)HID * 32;

    bf16x8 rA[8], rB[8];   // [0..3]=chunk0, [4..7]=chunk1

    #define LOAD_SLAB(R, S)                                                   \
        do {                                                                  \
            _Pragma("unroll")                                                 \
            for (int o = 0; o < 4; o++) {                                     \
                R[o]     = *(const bf16x8*)&bv[base0 + (S) * 8192 + o * 8];   \
                R[4 + o] = *(const bf16x8*)&bv[base1 + (S) * 8192 + o * 8];   \
            }                                                                 \
        } while (0)

    LOAD_SLAB(rA, 0);      // longest-latency first

    float aD[4], sd0[4], sd1[4];
    #pragma unroll
    for (int s = 0; s < 4; s++) {
        const int c = kBase + s * 256 + tid;
        aD[s]  = Adecay[c];
        sd0[s] = carries[(size_t)(batch * NCH + chunk0) * HID + c];
        sd1[s] = carries[(size_t)(batch * NCH + chunk0 + 1) * HID + c];
    }

    LOAD_SLAB(rB, 1);

    f32x4 acc[2][2][4] = {};

    #define SCAN_SLAB(R, S, PG)                                               \
        do {                                                                  \
            const float a = sigmoidf_dev(aD[S]);                              \
            float st0 = sd0[S], st1 = sd1[S];                                 \
            bf16_t* hw0 = &hs[PG][(tid >> 5) * CKSTRIDE];                     \
            bf16_t* hw1 = hw0 + CHOFF;                                        \
            const int cho = (tid >> 3) & 3, chi = tid & 7;                    \
            _Pragma("unroll")                                                 \
            for (int o = 0; o < 4; o++) {                                     \
                _Pragma("unroll")                                             \
                for (int j = 0; j < 8; j++) {                                 \
                    const int t = o * 8 + j;                                  \
                    const int sw = t * 32 + ((cho ^ ((t >> 2) & 3)) << 3) + chi; \
                    st0 = a * st0 + (float)R[o][j];                           \
                    hw0[sw] = (bf16_t)st0;                                    \
                    st1 = a * st1 + (float)R[4 + o][j];                       \
                    hw1[sw] = (bf16_t)st1;                                    \
                }                                                             \
            }                                                                 \
        } while (0)

    auto mfma_phase = [&](const bf16_t* hb, int s) {
        const int ksBase = (kBase >> 5) + s * 8;
        __builtin_amdgcn_s_setprio(1);
        #pragma unroll 2
        for (int cki = 0; cki < 8; cki++) {
            bf16x8 af[2][2], bfr[4];
            #pragma unroll
            for (int nt = 0; nt < 4; nt++)
                bfr[nt] = *(const bf16x8*)&Wt[
                    (((size_t)(ksBase + cki) * 16 + wave * 4 + nt) * 64 + lane) * 8];
            #pragma unroll
            for (int c = 0; c < 2; c++)
                #pragma unroll
                for (int mt = 0; mt < 2; mt++)
                    af[c][mt] = *(const bf16x8*)&hb[c * CHOFF + cki * CKSTRIDE
                                 + (mt * 16 + r16) * 32 + ((q ^ (r16 >> 2)) << 3)];
            #pragma unroll
            for (int c = 0; c < 2; c++)
                #pragma unroll
                for (int mt = 0; mt < 2; mt++)
                    #pragma unroll
                    for (int nt = 0; nt < 4; nt++)
                        acc[c][mt][nt] = __builtin_amdgcn_mfma_f32_16x16x32_bf16(
                            af[c][mt], bfr[nt], acc[c][mt][nt], 0, 0, 0);
        }
        __builtin_amdgcn_s_setprio(0);
    };

    // prologue: scan(0) exposed (nothing to overlap yet)
    SCAN_SLAB(rA, 0, 0);
    __syncthreads();

    // P1: load(2) || scan(1)->hs[1] || mfma(0, hs[0])
    LOAD_SLAB(rA, 2);
    SCAN_SLAB(rB, 1, 1);
    mfma_phase(&hs[0][0], 0);
    __syncthreads();

    // P2: load(3) || scan(2)->hs[0] || mfma(1, hs[1])
    LOAD_SLAB(rB, 3);
    SCAN_SLAB(rA, 2, 0);
    mfma_phase(&hs[1][0], 1);
    __syncthreads();

    // P3: scan(3)->hs[1] || mfma(2, hs[0])
    SCAN_SLAB(rB, 3, 1);
    mfma_phase(&hs[0][0], 2);
    __syncthreads();

    // P4: mfma(3, hs[1]); epilogue writes hs[0] (its readers drained at P3 barrier)
    mfma_phase(&hs[1][0], 3);
    #pragma unroll
    for (int nt = 0; nt < 4; nt++) {
        const int col = wave * 64 + nt * 16 + r16;
        #pragma unroll
        for (int c = 0; c < 2; c++)
            #pragma unroll
            for (int mt = 0; mt < 2; mt++)
                #pragma unroll
                for (int rg = 0; rg < 4; rg++)
                    hs[0][(c * 32 + mt * 16 + q * 4 + rg) * 264 + col] =
                        (bf16_t)acc[c][mt][nt][rg];
    }
    __syncthreads();

    bf16_t* Pb = P + (size_t)blockIdx.y * (BATCH * SEQ) * DIMSZ;
    #pragma unroll
    for (int p = 0; p < 8; p++) {
        const int task = p * 256 + tid;
        const int r = task >> 5, g8 = (task & 31) << 3;
        *(bf16x8*)&Pb[(size_t)(mBase + r) * DIMSZ + g8] =
            *(const bf16x8*)&hs[0][r * 264 + g8];
    }
    #undef LOAD_SLAB
    #undef SCAN_SLAB
}

// ---------------- reduce bf16 partials + bias -> fp32 d_out ----------------
__global__ void reduce_out_kernel(const bf16_t* __restrict__ P,
                                  const float* __restrict__ bias,
                                  float* __restrict__ out, int nTask) {
    int i = blockIdx.x * blockDim.x + threadIdx.x;   // M*256/8
    if (i >= nTask) return;
    int n8 = (i & 31) << 3;
    size_t off = (size_t)i * 8;
    float v[8];
    #pragma unroll
    for (int j = 0; j < 8; j++) v[j] = bias[n8 + j];
    #pragma unroll
    for (int sp = 0; sp < SPLITK2; sp++) {
        bf16x8 p = *(const bf16x8*)&P[(size_t)sp * (BATCH * SEQ) * DIMSZ + off];
        #pragma unroll
        for (int j = 0; j < 8; j++) v[j] += (float)p[j];
    }
    float4* o4 = (float4*)&out[off];
    o4[0] = make_float4(v[0], v[1], v[2], v[3]);
    o4[1] = make_float4(v[4], v[5], v[6], v[7]);
}

extern "C" void kernel_launch(void* const* d_in, const int* in_sizes, int n_in,
                              void* d_out, int out_size, void* d_ws, size_t ws_size,
                              hipStream_t stream)
{
    const float* x  = (const float*)d_in[0];
    const float* WB = (const float*)d_in[1];
    const float* bB = (const float*)d_in[2];
    const float* WC = (const float*)d_in[3];
    const float* bC = (const float*)d_in[4];
    const float* A  = (const float*)d_in[5];

    char* ws = (char*)d_ws;
    size_t off = 0;
    bf16_t* xt   = (bf16_t*)(ws + off); off += (size_t)BATCH * SEQ * DIMSZ * 2;  // 4 MB
    bf16_t* WBt  = (bf16_t*)(ws + off); off += (size_t)HID * DIMSZ * 2;          // 2 MB
    bf16_t* Wt   = (bf16_t*)(ws + off); off += (size_t)DIMSZ * HID * 2;          // 2 MB
    bf16_t* bbuf = (bf16_t*)(ws + off); off += (size_t)BATCH * SEQ * HID * 2;    // 64 MB, chunk-blocked
    bf16_t* partials = (bf16_t*)(ws + off); off += (size_t)SPLITK2 * BATCH * SEQ * DIMSZ * 2; // 16.75 MB
    float* totals   = (float*)(ws + off); off += (size_t)BATCH * NCH * HID * 4;
    float* carries  = (float*)(ws + off); off += (size_t)BATCH * NCH * HID * 4;

    const int M = BATCH * SEQ;   // 8192

    prep_kernel<<<2048, 256, 0, stream>>>(x, WB, WC, xt, WBt, Wt);

    dim3 g1(M / 128, HID / 128);
    gemm1_fused<<<g1, 256, 0, stream>>>(xt, WBt, bB, A, bbuf, totals);

    scan_carries_kernel<<<256, 64, 0, stream>>>(totals, A, carries);

    dim3 g2(M / BM2, SPLITK2);
    gemm2_fused<<<g2, 256, 0, stream>>>(bbuf, Wt, A, carries, partials);

    int nTask = M * DIMSZ / 8;
    reduce_out_kernel<<<(nTask + 255) / 256, 256, 0, stream>>>(
        partials, bC, (float*)d_out, nTask);
}